// Round 4
// baseline (129.993 us; speedup 1.0000x reference)
//
#include <hip/hip_runtime.h>

#define B_ 128
#define O_ 1024
#define I_ 1024
#define NCHUNK 64
#define CI (I_ / NCHUNK)     // 16 i-values per wave
#define WPB 4                // waves per block
#define TT_BYTES ((size_t)O_ * I_ * sizeof(float))

#define LOG2E_F  1.4426950408889634f
#define LN2_F    0.6931471805599453f
#define LN2SQ_F  0.4804530139182014f          // ln2^2
#define EPSC_F   (1e-7f * LN2SQ_F)            // eps * ln2^2

typedef float v2f __attribute__((ext_vector_type(2)));

__device__ __forceinline__ float fast_rsq(float x)  { return __builtin_amdgcn_rsqf(x); }
__device__ __forceinline__ float fast_exp2(float x) { return __builtin_amdgcn_exp2f(x); }
__device__ __forceinline__ float fast_rcp(float x)  { return __builtin_amdgcn_rcpf(x); }

// ---------------------------------------------------------------------------
// Kernel 1: Tt2[i*O + o] = T[o,i]^2, T = (ix/iy + la)*(1+lm) - ox/oy.
// ---------------------------------------------------------------------------
__global__ __launch_bounds__(256) void build_T2_kernel(
    const float* __restrict__ ix, const float* __restrict__ iy,
    const float* __restrict__ ox, const float* __restrict__ oy,
    const float* __restrict__ la, const float* __restrict__ lm,
    float* __restrict__ Tt2)
{
    __shared__ float tile[32][33];
    const int i0 = blockIdx.x * 32;
    const int o0 = blockIdx.y * 32;
    const int tx = threadIdx.x;
    const int ty = threadIdx.y;

#pragma unroll
    for (int r = 0; r < 32; r += 8) {
        const int o = o0 + ty + r;
        const int i = i0 + tx;
        const int idx = o * I_ + i;
        const float t = fmaf(ix[idx] * fast_rcp(iy[idx]) + la[idx],
                             1.0f + lm[idx],
                             -(ox[idx] * fast_rcp(oy[idx])));
        tile[ty + r][tx] = t * t;
    }
    __syncthreads();
#pragma unroll
    for (int r = 0; r < 32; r += 8) {
        const int i = i0 + ty + r;
        const int o = o0 + tx;
        Tt2[i * O_ + o] = tile[tx][ty + r];
    }
}

// ---------------------------------------------------------------------------
// Kernel 1b: minr2[i] = min_o Tt2[i,o] -> softmax max is rsqrt-monotone exact.
// ---------------------------------------------------------------------------
__global__ __launch_bounds__(64) void min_row_kernel(
    const float* __restrict__ Tt2, float* __restrict__ minr2)
{
    const int i = blockIdx.x;
    const int lane = threadIdx.x;
    const float4* row = (const float4*)(Tt2 + (size_t)i * O_);
    float mn = 3.4e38f;
#pragma unroll
    for (int k = 0; k < 4; ++k) {
        const float4 v = row[lane + 64 * k];
        mn = fminf(mn, fminf(fminf(v.x, v.y), fminf(v.z, v.w)));
    }
#pragma unroll
    for (int off = 32; off > 0; off >>= 1)
        mn = fminf(mn, __shfl_xor(mn, off));
    if (lane == 0) minr2[i] = mn;
}

// ---------------------------------------------------------------------------
// Kernel 2: wave owns chunk of 16 i's; lane owns 16 o's. Per-element math on
// packed float2 (v_pk_fma/add_f32, full-rate dual-FP32 on gfx950) — halves
// regular VALU issue slots. i-loop unrolled 2x with ping-pong register sets
// (no copy-out movs, two independent transc/reduce chains in flight).
// ---------------------------------------------------------------------------
__global__ __launch_bounds__(256) void aeg_main_kernel(
    const float* __restrict__ data,   // (B, I)
    const float* __restrict__ Tt2,    // (I, O) transposed T^2
    const float* __restrict__ minr2,  // (I) or nullptr
    float* __restrict__ out)          // (B, O), pre-zeroed
{
    __shared__ float red[WPB][O_];    // 16 KB

    const int w    = threadIdx.x >> 6;
    const int lane = threadIdx.x & 63;
    const int chunk = blockIdx.x * WPB + w;
    const int b     = blockIdx.y;

    const float* dptr = data + b * I_ + chunk * CI;
    const float4* rowbase = (const float4*)(Tt2 + (size_t)chunk * CI * O_);

    v2f acc2[8];
#pragma unroll
    for (int j = 0; j < 8; ++j) acc2[j] = (v2f)0.0f;

    auto load_row = [&](float4 (&r)[4], int ii) {
        const float4* row = rowbase + (size_t)ii * (O_ / 4);
#pragma unroll
        for (int k = 0; k < 4; ++k) r[k] = row[lane + 64 * k];
    };

    auto body = [&](const float4 (&r)[4], int ii) {
        const float dv = dptr[ii];
        const float sig = fast_rcp(1.0f + fast_exp2(-dv * LOG2E_F));
        const float sigc = sig * LN2_F;
        const float s2 = sigc * sigc;

        float mr2;
        if (minr2) {
            mr2 = minr2[chunk * CI + ii];
        } else {
            float mn = 3.4e38f;
#pragma unroll
            for (int k = 0; k < 4; ++k)
                mn = fminf(mn, fminf(fminf(r[k].x, r[k].y), fminf(r[k].z, r[k].w)));
#pragma unroll
            for (int off = 32; off > 0; off >>= 1)
                mn = fminf(mn, __shfl_xor(mn, off));
            mr2 = mn;
        }
        const float m2 = fast_rsq(fmaf(mr2, s2, EPSC_F));  // exact max (log2)

        const v2f s2v = {s2, s2};
        const v2f epv = {EPSC_F, EPSC_F};
        const v2f m2v = {m2, m2};

        v2f e2[8];
        v2f zv = (v2f)0.0f;
#pragma unroll
        for (int k = 0; k < 4; ++k) {
            const v2f a = {r[k].x, r[k].y};
            const v2f c = {r[k].z, r[k].w};
            const v2f q0 = a * s2v + epv;                  // v_pk_fma_f32
            const v2f q1 = c * s2v + epv;
            v2f t0, t1;
            t0.x = fast_rsq(q0.x); t0.y = fast_rsq(q0.y);
            t1.x = fast_rsq(q1.x); t1.y = fast_rsq(q1.y);
            t0 -= m2v;                                     // v_pk_add_f32
            t1 -= m2v;
            v2f ev0, ev1;
            ev0.x = fast_exp2(t0.x); ev0.y = fast_exp2(t0.y);
            ev1.x = fast_exp2(t1.x); ev1.y = fast_exp2(t1.y);
            e2[2 * k]     = ev0;
            e2[2 * k + 1] = ev1;
            zv += ev0;                                     // v_pk_add_f32
            zv += ev1;
        }
        float z = zv.x + zv.y;
#pragma unroll
        for (int off = 32; off > 0; off >>= 1)
            z += __shfl_xor(z, off);

        const float scale = dv * fast_rcp(z);              // z >= 1
        const v2f sc = {scale, scale};
#pragma unroll
        for (int j = 0; j < 8; ++j)
            acc2[j] = e2[j] * sc + acc2[j];                // v_pk_fma_f32
    };

    float4 rA[4], rB[4];
    load_row(rA, 0);
    for (int ii = 0; ii < CI; ii += 2) {
        load_row(rB, ii + 1);
        body(rA, ii);
        if (ii + 2 < CI) load_row(rA, ii + 2);
        body(rB, ii + 1);
    }

    // Stage per-wave accumulators, reduce across the 4 waves in LDS.
#pragma unroll
    for (int k = 0; k < 4; ++k) {
        float4 v;
        v.x = acc2[2 * k].x;     v.y = acc2[2 * k].y;
        v.z = acc2[2 * k + 1].x; v.w = acc2[2 * k + 1].y;
        ((float4*)&red[w][256 * k])[lane] = v;
    }
    __syncthreads();

    const int t = threadIdx.x;       // 0..255, each sums 4 consecutive o's
    float4 v = ((const float4*)red[0])[t];
#pragma unroll
    for (int ww = 1; ww < WPB; ++ww) {
        const float4 u = ((const float4*)red[ww])[t];
        v.x += u.x; v.y += u.y; v.z += u.z; v.w += u.w;
    }
    float* ob = out + b * O_ + 4 * t;
    atomicAdd(&ob[0], v.x);
    atomicAdd(&ob[1], v.y);
    atomicAdd(&ob[2], v.z);
    atomicAdd(&ob[3], v.w);
}

// ---------------------------------------------------------------------------
extern "C" void kernel_launch(void* const* d_in, const int* in_sizes, int n_in,
                              void* d_out, int out_size, void* d_ws, size_t ws_size,
                              hipStream_t stream)
{
    const float* data = (const float*)d_in[0];
    const float* ix   = (const float*)d_in[1];
    const float* iy   = (const float*)d_in[2];
    const float* ox   = (const float*)d_in[3];
    const float* oy   = (const float*)d_in[4];
    const float* la   = (const float*)d_in[5];
    const float* lm   = (const float*)d_in[6];
    float* out  = (float*)d_out;
    float* Tt2  = (float*)d_ws;
    float* minr2 = (ws_size >= TT_BYTES + I_ * sizeof(float))
                       ? (float*)((char*)d_ws + TT_BYTES) : nullptr;

    hipMemsetAsync(d_out, 0, (size_t)B_ * O_ * sizeof(float), stream);

    build_T2_kernel<<<dim3(I_ / 32, O_ / 32), dim3(32, 8), 0, stream>>>(
        ix, iy, ox, oy, la, lm, Tt2);

    if (minr2)
        min_row_kernel<<<I_, 64, 0, stream>>>(Tt2, minr2);

    aeg_main_kernel<<<dim3(NCHUNK / WPB, B_), 256, 0, stream>>>(
        data, Tt2, minr2, out);
}

// Round 6
// 121.287 us; speedup vs baseline: 1.0718x; 1.0718x over previous
//
#include <hip/hip_runtime.h>

#define B_ 128
#define O_ 1024
#define I_ 1024
#define NCHUNK 64
#define CI (I_ / NCHUNK)     // 16 i-values per wave
#define WPB 4                // waves per block
#define TT_BYTES ((size_t)O_ * I_ * sizeof(float))

#define LOG2E_F  1.4426950408889634f
#define LN2_F    0.6931471805599453f
#define LN2SQ_F  0.4804530139182014f          // ln2^2
#define EPSC_F   (1e-7f * LN2SQ_F)            // eps * ln2^2

typedef float v2f __attribute__((ext_vector_type(2)));

__device__ __forceinline__ float fast_rsq(float x)  { return __builtin_amdgcn_rsqf(x); }
__device__ __forceinline__ float fast_exp2(float x) { return __builtin_amdgcn_exp2f(x); }
__device__ __forceinline__ float fast_rcp(float x)  { return __builtin_amdgcn_rcpf(x); }

// wave-uniform value -> SGPR
__device__ __forceinline__ float rfl(float x) {
    return __builtin_bit_cast(float,
        __builtin_amdgcn_readfirstlane(__builtin_bit_cast(int, x)));
}

// DPP add step (ctrl must be an immediate -> template param);
// bound_ctrl=true: invalid sources read 0.
template <int CTRL>
__device__ __forceinline__ float dpp_add(float v) {
    int x = __builtin_amdgcn_update_dpp(0, __builtin_bit_cast(int, v),
                                        CTRL, 0xf, 0xf, true);
    return v + __builtin_bit_cast(float, x);
}
// 64-lane sum; total lands in lane 63, returned as SGPR-uniform float.
__device__ __forceinline__ float wave_sum_uniform(float v) {
    v = dpp_add<0xB1>(v);   // quad_perm [1,0,3,2] : pair sums
    v = dpp_add<0x4E>(v);   // quad_perm [2,3,0,1] : quad sums
    v = dpp_add<0x141>(v);  // row_half_mirror     : octet sums
    v = dpp_add<0x140>(v);  // row_mirror          : row-of-16 sums
    v = dpp_add<0x142>(v);  // row_bcast15         : rows 1..3 += prev row
    v = dpp_add<0x143>(v);  // row_bcast31         : rows 2,3 += rows 0+1
    return __builtin_bit_cast(float,
        __builtin_amdgcn_readlane(__builtin_bit_cast(int, v), 63));
}

// ---------------------------------------------------------------------------
// Fused kernel 1: Tt2[i*O+o] = T[o,i]^2 (transposed+squared), plus
//  - per-column(i) min via LDS-pre-reduced global atomicMin on uint bits
//    (valid: r2 >= 0 so float bits are monotone as unsigned),
//  - zeroing of d_out (grid 1024 blocks x 128 elems = 131072 = B*O).
// ---------------------------------------------------------------------------
__global__ __launch_bounds__(256) void build_T2_kernel(
    const float* __restrict__ ix, const float* __restrict__ iy,
    const float* __restrict__ ox, const float* __restrict__ oy,
    const float* __restrict__ la, const float* __restrict__ lm,
    float* __restrict__ Tt2, unsigned* __restrict__ minbits,
    float* __restrict__ out_zero)
{
    __shared__ float tile[32][33];
    __shared__ unsigned mloc[32];
    const int i0 = blockIdx.x * 32;
    const int o0 = blockIdx.y * 32;
    const int tx = threadIdx.x;      // 0..31
    const int ty = threadIdx.y;      // 0..7
    const int t  = ty * 32 + tx;     // 0..255

    if (t < 32) mloc[t] = 0xFFFFFFFFu;

    // fold the d_out zeroing in (saves a memset dispatch)
    const int bid = blockIdx.y * gridDim.x + blockIdx.x;   // 0..1023
    if (t < 128) out_zero[bid * 128 + t] = 0.0f;

#pragma unroll
    for (int r = 0; r < 32; r += 8) {
        const int o = o0 + ty + r;
        const int i = i0 + tx;
        const int idx = o * I_ + i;
        const float tt = fmaf(ix[idx] * fast_rcp(iy[idx]) + la[idx],
                              1.0f + lm[idx],
                              -(ox[idx] * fast_rcp(oy[idx])));
        tile[ty + r][tx] = tt * tt;
    }
    __syncthreads();
#pragma unroll
    for (int r = 0; r < 32; r += 8) {
        const int i = i0 + ty + r;
        const int o = o0 + tx;
        Tt2[i * O_ + o] = tile[tx][ty + r];
    }
    // per-i min over this block's 32 o's: thread t covers i_local=t&31,
    // o_locals = (t>>5)*4 .. +3
    const int il = t & 31;
    const int g  = t >> 5;
    float mn = fminf(fminf(tile[4 * g + 0][il], tile[4 * g + 1][il]),
                     fminf(tile[4 * g + 2][il], tile[4 * g + 3][il]));
    atomicMin(&mloc[il], __builtin_bit_cast(unsigned, mn));
    __syncthreads();
    if (t < 32) atomicMin(&minbits[i0 + t], mloc[t]);
}

// ---------------------------------------------------------------------------
// Kernel 2: wave owns chunk of 16 i's; lane owns 16 o's. Prologue hoists all
// wave-uniform per-i values (dv, s2c=(sig*ln2)^2, m2=exact softmax max in
// log2 units) into SGPRs — no memory load sits on the per-body critical
// path. z-reduce via DPP (short serial chain). Fully unrolled i-loop with
// ping-pong row prefetch; packed f32 math elsewhere.
// ---------------------------------------------------------------------------
__global__ __launch_bounds__(256) void aeg_main_kernel(
    const float* __restrict__ data,   // (B, I)
    const float* __restrict__ Tt2,    // (I, O) transposed T^2
    const float* __restrict__ minr2,  // (I) float bits (from atomicMin)
    float* __restrict__ out)          // (B, O), zeroed by build_T2
{
    __shared__ float red[WPB][O_];    // 16 KB

    const int w    = threadIdx.x >> 6;
    const int lane = threadIdx.x & 63;
    const int chunk = blockIdx.x * WPB + w;
    const int b     = blockIdx.y;

    const float4* rowbase = (const float4*)(Tt2 + (size_t)chunk * CI * O_);

    // ---- prologue: hoist all wave-uniform loads/derivations into SGPRs ----
    const float4* dv4 = (const float4*)(data + b * I_ + chunk * CI);
    const float4* mr4 = (const float4*)(minr2 + chunk * CI);
    float dvf[CI], mrf[CI];
#pragma unroll
    for (int k = 0; k < 4; ++k) {
        const float4 a = dv4[k];
        const float4 m = mr4[k];
        dvf[4 * k + 0] = a.x; dvf[4 * k + 1] = a.y;
        dvf[4 * k + 2] = a.z; dvf[4 * k + 3] = a.w;
        mrf[4 * k + 0] = m.x; mrf[4 * k + 1] = m.y;
        mrf[4 * k + 2] = m.z; mrf[4 * k + 3] = m.w;
    }
    float sdv[CI], ss2[CI], sm2[CI];
#pragma unroll
    for (int j = 0; j < CI; ++j) {
        const float dv  = dvf[j];
        const float sig = fast_rcp(1.0f + fast_exp2(-dv * LOG2E_F));
        const float sc  = sig * LN2_F;
        const float s2  = sc * sc;
        const float m2  = fast_rsq(fmaf(mrf[j], s2, EPSC_F)); // exact max
        sdv[j] = rfl(dv);
        ss2[j] = rfl(s2);
        sm2[j] = rfl(m2);
    }

    v2f acc2[8];
#pragma unroll
    for (int j = 0; j < 8; ++j) acc2[j] = (v2f)0.0f;

    float4 rr[2][4];
#pragma unroll
    for (int k = 0; k < 4; ++k) rr[0][k] = rowbase[lane + 64 * k];

#pragma unroll
    for (int ii = 0; ii < CI; ++ii) {
        if (ii + 1 < CI) {
            const float4* nrow = rowbase + (size_t)(ii + 1) * (O_ / 4);
#pragma unroll
            for (int k = 0; k < 4; ++k) rr[(ii + 1) & 1][k] = nrow[lane + 64 * k];
        }
        const float4* r = rr[ii & 1];
        const v2f s2v = {ss2[ii], ss2[ii]};
        const v2f m2v = {sm2[ii], sm2[ii]};
        const v2f epv = {EPSC_F, EPSC_F};

        v2f e2[8];
        v2f zv0 = (v2f)0.0f, zv1 = (v2f)0.0f;
#pragma unroll
        for (int k = 0; k < 4; ++k) {
            const v2f a = {r[k].x, r[k].y};
            const v2f c = {r[k].z, r[k].w};
            const v2f q0 = a * s2v + epv;
            const v2f q1 = c * s2v + epv;
            v2f t0, t1;
            t0.x = fast_rsq(q0.x); t0.y = fast_rsq(q0.y);
            t1.x = fast_rsq(q1.x); t1.y = fast_rsq(q1.y);
            t0 -= m2v;
            t1 -= m2v;
            v2f ev0, ev1;
            ev0.x = fast_exp2(t0.x); ev0.y = fast_exp2(t0.y);
            ev1.x = fast_exp2(t1.x); ev1.y = fast_exp2(t1.y);
            e2[2 * k]     = ev0;
            e2[2 * k + 1] = ev1;
            zv0 += ev0;
            zv1 += ev1;
        }
        const v2f zv = zv0 + zv1;
        const float zt = wave_sum_uniform(zv.x + zv.y);    // SGPR-uniform
        const float scale = sdv[ii] * fast_rcp(zt);        // z >= 1
        const v2f sc2 = {scale, scale};
#pragma unroll
        for (int j = 0; j < 8; ++j)
            acc2[j] = e2[j] * sc2 + acc2[j];
    }

    // Stage per-wave accumulators, reduce across the 4 waves in LDS.
#pragma unroll
    for (int k = 0; k < 4; ++k) {
        float4 v;
        v.x = acc2[2 * k].x;     v.y = acc2[2 * k].y;
        v.z = acc2[2 * k + 1].x; v.w = acc2[2 * k + 1].y;
        ((float4*)&red[w][256 * k])[lane] = v;
    }
    __syncthreads();

    const int t = threadIdx.x;
    float4 v = ((const float4*)red[0])[t];
#pragma unroll
    for (int ww = 1; ww < WPB; ++ww) {
        const float4 u = ((const float4*)red[ww])[t];
        v.x += u.x; v.y += u.y; v.z += u.z; v.w += u.w;
    }
    float* ob = out + b * O_ + 4 * t;
    atomicAdd(&ob[0], v.x);
    atomicAdd(&ob[1], v.y);
    atomicAdd(&ob[2], v.z);
    atomicAdd(&ob[3], v.w);
}

// ---------------------------------------------------------------------------
extern "C" void kernel_launch(void* const* d_in, const int* in_sizes, int n_in,
                              void* d_out, int out_size, void* d_ws, size_t ws_size,
                              hipStream_t stream)
{
    const float* data = (const float*)d_in[0];
    const float* ix   = (const float*)d_in[1];
    const float* iy   = (const float*)d_in[2];
    const float* ox   = (const float*)d_in[3];
    const float* oy   = (const float*)d_in[4];
    const float* la   = (const float*)d_in[5];
    const float* lm   = (const float*)d_in[6];
    float* out  = (float*)d_out;
    float* Tt2  = (float*)d_ws;
    unsigned* minbits = (unsigned*)((char*)d_ws + TT_BYTES);

    // init min accumulators to UINT_MAX (tiny; the only extra dispatch)
    (void)hipMemsetAsync(minbits, 0xFF, I_ * sizeof(unsigned), stream);

    build_T2_kernel<<<dim3(I_ / 32, O_ / 32), dim3(32, 8), 0, stream>>>(
        ix, iy, ox, oy, la, lm, Tt2, minbits, out);

    aeg_main_kernel<<<dim3(NCHUNK / WPB, B_), 256, 0, stream>>>(
        data, Tt2, (const float*)minbits, out);
}